// Round 1
// baseline (327.745 us; speedup 1.0000x reference)
//
#include <hip/hip_runtime.h>
#include <hip/hip_bf16.h>
#include <math.h>

typedef __bf16 bf16;
typedef __bf16 bf16x4 __attribute__((ext_vector_type(4)));
typedef __bf16 bf16x8 __attribute__((ext_vector_type(8)));
typedef float  f32x4  __attribute__((ext_vector_type(4)));

#define S_LEN 2048
#define EMB   2048
#define NH    16
#define NKV   4
#define HD    128
#define FQKV  3072  /* NH*HD + 2*NKV*HD */

__device__ __forceinline__ f32x4 mfma16(bf16x8 a, bf16x8 b, f32x4 c) {
  return __builtin_amdgcn_mfma_f32_16x16x32_bf16(a, b, c, 0, 0, 0);
}

// ---------------- f32 -> bf16 convert, 4-wide ----------------
__global__ void cvt_kernel(const float* __restrict__ in, bf16* __restrict__ out, int n4) {
  int i = blockIdx.x * blockDim.x + threadIdx.x;
  const int stride = gridDim.x * blockDim.x;
  for (; i < n4; i += stride) {
    float4 v = reinterpret_cast<const float4*>(in)[i];
    bf16x4 o;
    o[0] = (bf16)v.x; o[1] = (bf16)v.y; o[2] = (bf16)v.z; o[3] = (bf16)v.w;
    reinterpret_cast<bf16x4*>(out)[i] = o;
  }
}

// ---------------- GEMM: C[M][N] = A[M][K] * B[N][K]^T (both row-major in K) ----------------
// 128x128 tile, BK=64, 4 waves (each 32 rows x 128 cols), 16x16x32 bf16 MFMA.
// LDS XOR-swizzled (chunk ^= row&7, 16B chunks) via pre-swizzled global source,
// since global_load_lds writes linearly (base + lane*16).
// mode 0: fused RoPE/split epilogue -> qb[h][s][d], kb[kh][s][d], vtb[kh][d][s] (bf16)
// mode 1: plain f32 store to outf[row*N + col]
__global__ __launch_bounds__(256, 2) void gemm_bt(
    const bf16* __restrict__ A, const bf16* __restrict__ B,
    int M, int N, int K, int mode,
    bf16* __restrict__ qb, bf16* __restrict__ kb, bf16* __restrict__ vtb,
    float* __restrict__ outf)
{
  __shared__ __align__(16) bf16 As[128 * 64];
  __shared__ __align__(16) bf16 Bs[128 * 64];
  const int tid = threadIdx.x;
  const int w  = tid >> 6;
  const int l  = tid & 63;
  const int li = l & 15, lh = l >> 4;
  const int m0 = blockIdx.y * 128, n0 = blockIdx.x * 128;

  f32x4 acc[2][8];
#pragma unroll
  for (int i = 0; i < 2; ++i)
#pragma unroll
    for (int j = 0; j < 8; ++j) acc[i][j] = f32x4{0.f, 0.f, 0.f, 0.f};

  const int srow = l >> 3;   // row within an 8-row staging group
  const int schk = l & 7;    // 16B chunk within a 64-col row

  for (int k0 = 0; k0 < K; k0 += 64) {
#pragma unroll
    for (int i = 0; i < 4; ++i) {
      const int row = i * 32 + w * 8 + srow;
      const int sch = schk ^ (row & 7);
      const bf16* ga = A + (size_t)(m0 + row) * K + (k0 + sch * 8);
      const bf16* gb = B + (size_t)(n0 + row) * K + (k0 + sch * 8);
      bf16* la = As + (i * 32 + w * 8) * 64;
      bf16* lb = Bs + (i * 32 + w * 8) * 64;
      __builtin_amdgcn_global_load_lds((const __attribute__((address_space(1))) void*)ga,
                                       (__attribute__((address_space(3))) void*)la, 16, 0, 0);
      __builtin_amdgcn_global_load_lds((const __attribute__((address_space(1))) void*)gb,
                                       (__attribute__((address_space(3))) void*)lb, 16, 0, 0);
    }
    __syncthreads();
#pragma unroll
    for (int kc = 0; kc < 2; ++kc) {
      bf16x8 afr[2], bfr[8];
#pragma unroll
      for (int mt = 0; mt < 2; ++mt) {
        const int mr = w * 32 + mt * 16 + li;
        const int c  = (kc * 4 + lh) ^ (mr & 7);
        afr[mt] = *reinterpret_cast<const bf16x8*>((const char*)As + mr * 128 + c * 16);
      }
#pragma unroll
      for (int nt = 0; nt < 8; ++nt) {
        const int nr = nt * 16 + li;
        const int c  = (kc * 4 + lh) ^ (nr & 7);
        bfr[nt] = *reinterpret_cast<const bf16x8*>((const char*)Bs + nr * 128 + c * 16);
      }
#pragma unroll
      for (int nt = 0; nt < 8; ++nt) {
        acc[0][nt] = mfma16(afr[0], bfr[nt], acc[0][nt]);
        acc[1][nt] = mfma16(afr[1], bfr[nt], acc[1][nt]);
      }
    }
    __syncthreads();
  }

  // ---- epilogue ----
  const int row_base = m0 + w * 32;
  if (mode == 1) {
#pragma unroll
    for (int mt = 0; mt < 2; ++mt)
#pragma unroll
      for (int nt = 0; nt < 8; ++nt)
#pragma unroll
        for (int r = 0; r < 4; ++r) {
          const int sr = row_base + mt * 16 + lh * 4 + r;
          const int sc = n0 + nt * 16 + li;
          outf[(size_t)sr * N + sc] = acc[mt][nt][r];
        }
  } else {
    int seg, hh;
    if (n0 < NH * HD)            { seg = 0; hh = n0 >> 7; }
    else if (n0 < (NH + NKV) * HD){ seg = 1; hh = (n0 - NH * HD) >> 7; }
    else                          { seg = 2; hh = (n0 - (NH + NKV) * HD) >> 7; }

    if (seg == 2) {  // V: store transposed vtb[kh][d][s], pack 4 consecutive s
#pragma unroll
      for (int mt = 0; mt < 2; ++mt)
#pragma unroll
        for (int nt = 0; nt < 8; ++nt) {
          const int d = nt * 16 + li;
          const int sb = row_base + mt * 16 + lh * 4;
          bf16x4 pk;
#pragma unroll
          for (int r = 0; r < 4; ++r) pk[r] = (bf16)acc[mt][nt][r];
          *reinterpret_cast<bf16x4*>(vtb + (size_t)hh * HD * S_LEN + (size_t)d * S_LEN + sb) = pk;
        }
    } else {  // Q or K: RoPE (+ 1/sqrt(D) folded into Q)
      float invf[4];
#pragma unroll
      for (int j = 0; j < 4; ++j)
        invf[j] = exp2f(-(float)(j * 16 + li) * (13.287712379549449f / 64.0f)); // 10000^(-i/64)
      bf16* dst = (seg == 0) ? (qb + (size_t)hh * S_LEN * HD)
                             : (kb + (size_t)hh * S_LEN * HD);
      const float qscale = (seg == 0) ? 0.08838834764831845f : 1.0f;
#pragma unroll
      for (int mt = 0; mt < 2; ++mt)
#pragma unroll
        for (int r = 0; r < 4; ++r) {
          const int spos = row_base + mt * 16 + lh * 4 + r;
          float cs[4], sn[4];
#pragma unroll
          for (int j = 0; j < 4; ++j) sincosf((float)spos * invf[j], &sn[j], &cs[j]);
#pragma unroll
          for (int nt = 0; nt < 8; ++nt) {
            const int d = nt * 16 + li;
            const int j = nt & 3;
            const float x = acc[mt][nt][r];
            const float prt = acc[mt][nt ^ 4][r];
            const float rot = (nt < 4) ? -prt : prt;
            const float y = (x * cs[j] + rot * sn[j]) * qscale;
            dst[(size_t)spos * HD + d] = (bf16)y;
          }
        }
    }
  }
}

// ---------------- flash attention: 1 wave per (16 q-rows, head) ----------------
// Q pre-scaled by 1/sqrt(D). K rope'd. V stored transposed [kh][d][s].
__global__ __launch_bounds__(64) void attn_kernel(
    const bf16* __restrict__ qb, const bf16* __restrict__ kb, const bf16* __restrict__ vtb,
    bf16* __restrict__ ctx)
{
  __shared__ __align__(16) bf16 Pl[16 * 32];
  const int l  = threadIdx.x;
  const int li = l & 15, lh = l >> 4;
  const int q0 = blockIdx.x * 16;
  const int h  = blockIdx.y;
  const int kh = h >> 2;   // rep = H/KVH = 4

  const bf16* Qh = qb + (size_t)h * S_LEN * HD;
  const bf16* Kh = kb + (size_t)kh * S_LEN * HD;
  const bf16* Vh = vtb + (size_t)kh * HD * S_LEN;

  bf16x8 aq[4];
#pragma unroll
  for (int kc = 0; kc < 4; ++kc)
    aq[kc] = *reinterpret_cast<const bf16x8*>(Qh + (size_t)(q0 + li) * HD + kc * 32 + lh * 8);

  f32x4 o[8];
#pragma unroll
  for (int i = 0; i < 8; ++i) o[i] = f32x4{0.f, 0.f, 0.f, 0.f};
  float mrow[4] = {-__builtin_inff(), -__builtin_inff(), -__builtin_inff(), -__builtin_inff()};
  float lrow[4] = {0.f, 0.f, 0.f, 0.f};
  const float L2E = 1.4426950408889634f;

  for (int kv0 = 0; kv0 < q0 + 16; kv0 += 32) {
    f32x4 sacc[2];
    sacc[0] = f32x4{0.f, 0.f, 0.f, 0.f};
    sacc[1] = f32x4{0.f, 0.f, 0.f, 0.f};
#pragma unroll
    for (int n = 0; n < 2; ++n)
#pragma unroll
      for (int kc = 0; kc < 4; ++kc) {
        bf16x8 bk = *reinterpret_cast<const bf16x8*>(
            Kh + (size_t)(kv0 + n * 16 + li) * HD + kc * 32 + lh * 8);
        sacc[n] = mfma16(aq[kc], bk, sacc[n]);
      }
    if (kv0 + 31 > q0) {  // causal mask needed on this tile
#pragma unroll
      for (int n = 0; n < 2; ++n)
#pragma unroll
        for (int r = 0; r < 4; ++r) {
          const int kv = kv0 + n * 16 + li;
          const int qq = q0 + lh * 4 + r;
          if (kv > qq) sacc[n][r] = -__builtin_inff();
        }
    }
    // online softmax (rows live on 16-lane groups; regs are rows)
    float sc[4], pm[4];
#pragma unroll
    for (int r = 0; r < 4; ++r) {
      float v = fmaxf(sacc[0][r], sacc[1][r]);
#pragma unroll
      for (int m = 1; m <= 8; m <<= 1) v = fmaxf(v, __shfl_xor(v, m));
      const float mn = fmaxf(mrow[r], v);
      sc[r] = exp2f((mrow[r] - mn) * L2E);
      mrow[r] = mn; pm[r] = mn;
    }
    float p[2][4];
#pragma unroll
    for (int r = 0; r < 4; ++r) {
      p[0][r] = exp2f((sacc[0][r] - pm[r]) * L2E);
      p[1][r] = exp2f((sacc[1][r] - pm[r]) * L2E);
      float s2 = p[0][r] + p[1][r];
#pragma unroll
      for (int m = 1; m <= 8; m <<= 1) s2 += __shfl_xor(s2, m);
      lrow[r] = lrow[r] * sc[r] + s2;
    }
#pragma unroll
    for (int dt = 0; dt < 8; ++dt)
#pragma unroll
      for (int r = 0; r < 4; ++r) o[dt][r] *= sc[r];
    // P -> LDS (C-layout positions), read back as A-fragment
    __syncthreads();
#pragma unroll
    for (int n = 0; n < 2; ++n)
#pragma unroll
      for (int r = 0; r < 4; ++r)
        Pl[(lh * 4 + r) * 32 + n * 16 + li] = (bf16)p[n][r];
    __syncthreads();
    const bf16x8 pa = *reinterpret_cast<const bf16x8*>(Pl + li * 32 + lh * 8);
#pragma unroll
    for (int dt = 0; dt < 8; ++dt) {
      bf16x8 bv = *reinterpret_cast<const bf16x8*>(
          Vh + (size_t)(dt * 16 + li) * S_LEN + kv0 + lh * 8);
      o[dt] = mfma16(pa, bv, o[dt]);
    }
  }
  // epilogue: normalize, write ctx[s][h*HD + d] bf16
#pragma unroll
  for (int dt = 0; dt < 8; ++dt)
#pragma unroll
    for (int r = 0; r < 4; ++r) {
      const int sr = q0 + lh * 4 + r;
      const int d  = dt * 16 + li;
      ctx[(size_t)sr * (NH * HD) + h * HD + d] = (bf16)(o[dt][r] / lrow[r]);
    }
}

extern "C" void kernel_launch(void* const* d_in, const int* in_sizes, int n_in,
                              void* d_out, int out_size, void* d_ws, size_t ws_size,
                              hipStream_t stream)
{
  const float* x       = (const float*)d_in[0];
  const float* w_qkv   = (const float*)d_in[1];
  const float* w_dense = (const float*)d_in[2];
  float* out = (float*)d_out;

  char* ws = (char*)d_ws;
  size_t off = 0;
  bf16* xb    = (bf16*)(ws + off); off += (size_t)S_LEN * EMB * 2;
  bf16* wqkvb = (bf16*)(ws + off); off += (size_t)FQKV * EMB * 2;
  bf16* wdb   = (bf16*)(ws + off); off += (size_t)EMB * EMB * 2;
  bf16* qbuf  = (bf16*)(ws + off); off += (size_t)NH  * S_LEN * HD * 2;
  bf16* kbuf  = (bf16*)(ws + off); off += (size_t)NKV * S_LEN * HD * 2;
  bf16* vtbuf = (bf16*)(ws + off); off += (size_t)NKV * HD * S_LEN * 2;
  bf16* ctxb  = (bf16*)(ws + off); off += (size_t)S_LEN * NH * HD * 2;
  (void)ws_size; (void)in_sizes; (void)n_in; (void)out_size;

  cvt_kernel<<<2048, 256, 0, stream>>>(x,       xb,    S_LEN * EMB / 4);
  cvt_kernel<<<2048, 256, 0, stream>>>(w_qkv,   wqkvb, FQKV * EMB / 4);
  cvt_kernel<<<2048, 256, 0, stream>>>(w_dense, wdb,   EMB * EMB / 4);

  gemm_bt<<<dim3(FQKV / 128, S_LEN / 128), 256, 0, stream>>>(
      xb, wqkvb, S_LEN, FQKV, EMB, 0, qbuf, kbuf, vtbuf, nullptr);

  attn_kernel<<<dim3(S_LEN / 16, NH), 64, 0, stream>>>(qbuf, kbuf, vtbuf, ctxb);

  gemm_bt<<<dim3(EMB / 128, S_LEN / 128), 256, 0, stream>>>(
      ctxb, wdb, S_LEN, EMB, NH * HD, 1, nullptr, nullptr, nullptr, out);
}

// Round 2
// 284.827 us; speedup vs baseline: 1.1507x; 1.1507x over previous
//
#include <hip/hip_runtime.h>
#include <hip/hip_bf16.h>
#include <math.h>

typedef __bf16 bf16;
typedef __bf16 bf16x4 __attribute__((ext_vector_type(4)));
typedef __bf16 bf16x8 __attribute__((ext_vector_type(8)));
typedef float  f32x4  __attribute__((ext_vector_type(4)));

#define S_LEN 2048
#define EMB   2048
#define NH    16
#define NKV   4
#define HD    128
#define FQKV  3072  /* NH*HD + 2*NKV*HD */

__device__ __forceinline__ f32x4 mfma16(bf16x8 a, bf16x8 b, f32x4 c) {
  return __builtin_amdgcn_mfma_f32_16x16x32_bf16(a, b, c, 0, 0, 0);
}

// ---------------- f32 -> bf16 convert, 4-wide ----------------
__global__ void cvt_kernel(const float* __restrict__ in, bf16* __restrict__ out, int n4) {
  int i = blockIdx.x * blockDim.x + threadIdx.x;
  const int stride = gridDim.x * blockDim.x;
  for (; i < n4; i += stride) {
    float4 v = reinterpret_cast<const float4*>(in)[i];
    bf16x4 o;
    o[0] = (bf16)v.x; o[1] = (bf16)v.y; o[2] = (bf16)v.z; o[3] = (bf16)v.w;
    reinterpret_cast<bf16x4*>(out)[i] = o;
  }
}

// ---------------- GEMM: C[M][N] = A[M][K] * B[N][K]^T (both row-major in K) ----------------
// 128x128 tile, BK=64, 4 waves (each 32 rows x 128 cols), 16x16x32 bf16 MFMA.
// LDS XOR-swizzled (chunk ^= row&7, 16B chunks) via pre-swizzled global source,
// since global_load_lds writes linearly (base + lane*16).
// mode 0: fused RoPE/split epilogue -> qb[h][s][d], kb[kh][s][d], vtb[kh][d][s] (bf16)
// mode 1: plain f32 store to outf[row*N + col]
__global__ __launch_bounds__(256, 2) void gemm_bt(
    const bf16* __restrict__ A, const bf16* __restrict__ B,
    int M, int N, int K, int mode,
    bf16* __restrict__ qb, bf16* __restrict__ kb, bf16* __restrict__ vtb,
    float* __restrict__ outf)
{
  __shared__ __align__(16) bf16 As[128 * 64];
  __shared__ __align__(16) bf16 Bs[128 * 64];
  const int tid = threadIdx.x;
  const int w  = tid >> 6;
  const int l  = tid & 63;
  const int li = l & 15, lh = l >> 4;
  const int m0 = blockIdx.y * 128, n0 = blockIdx.x * 128;

  f32x4 acc[2][8];
#pragma unroll
  for (int i = 0; i < 2; ++i)
#pragma unroll
    for (int j = 0; j < 8; ++j) acc[i][j] = f32x4{0.f, 0.f, 0.f, 0.f};

  const int srow = l >> 3;   // row within an 8-row staging group
  const int schk = l & 7;    // 16B chunk within a 64-col row

  for (int k0 = 0; k0 < K; k0 += 64) {
#pragma unroll
    for (int i = 0; i < 4; ++i) {
      const int row = i * 32 + w * 8 + srow;
      const int sch = schk ^ (row & 7);
      const bf16* ga = A + (size_t)(m0 + row) * K + (k0 + sch * 8);
      const bf16* gb = B + (size_t)(n0 + row) * K + (k0 + sch * 8);
      bf16* la = As + (i * 32 + w * 8) * 64;
      bf16* lb = Bs + (i * 32 + w * 8) * 64;
      __builtin_amdgcn_global_load_lds((const __attribute__((address_space(1))) void*)ga,
                                       (__attribute__((address_space(3))) void*)la, 16, 0, 0);
      __builtin_amdgcn_global_load_lds((const __attribute__((address_space(1))) void*)gb,
                                       (__attribute__((address_space(3))) void*)lb, 16, 0, 0);
    }
    __syncthreads();
#pragma unroll
    for (int kc = 0; kc < 2; ++kc) {
      bf16x8 afr[2], bfr[8];
#pragma unroll
      for (int mt = 0; mt < 2; ++mt) {
        const int mr = w * 32 + mt * 16 + li;
        const int c  = (kc * 4 + lh) ^ (mr & 7);
        afr[mt] = *reinterpret_cast<const bf16x8*>((const char*)As + mr * 128 + c * 16);
      }
#pragma unroll
      for (int nt = 0; nt < 8; ++nt) {
        const int nr = nt * 16 + li;
        const int c  = (kc * 4 + lh) ^ (nr & 7);
        bfr[nt] = *reinterpret_cast<const bf16x8*>((const char*)Bs + nr * 128 + c * 16);
      }
#pragma unroll
      for (int nt = 0; nt < 8; ++nt) {
        acc[0][nt] = mfma16(afr[0], bfr[nt], acc[0][nt]);
        acc[1][nt] = mfma16(afr[1], bfr[nt], acc[1][nt]);
      }
    }
    __syncthreads();
  }

  // ---- epilogue ----
  const int row_base = m0 + w * 32;
  if (mode == 1) {
#pragma unroll
    for (int mt = 0; mt < 2; ++mt)
#pragma unroll
      for (int nt = 0; nt < 8; ++nt)
#pragma unroll
        for (int r = 0; r < 4; ++r) {
          const int sr = row_base + mt * 16 + lh * 4 + r;
          const int sc = n0 + nt * 16 + li;
          outf[(size_t)sr * N + sc] = acc[mt][nt][r];
        }
  } else {
    int seg, hh;
    if (n0 < NH * HD)            { seg = 0; hh = n0 >> 7; }
    else if (n0 < (NH + NKV) * HD){ seg = 1; hh = (n0 - NH * HD) >> 7; }
    else                          { seg = 2; hh = (n0 - (NH + NKV) * HD) >> 7; }

    if (seg == 2) {  // V: store transposed vtb[kh][d][s], pack 4 consecutive s
#pragma unroll
      for (int mt = 0; mt < 2; ++mt)
#pragma unroll
        for (int nt = 0; nt < 8; ++nt) {
          const int d = nt * 16 + li;
          const int sb = row_base + mt * 16 + lh * 4;
          bf16x4 pk;
#pragma unroll
          for (int r = 0; r < 4; ++r) pk[r] = (bf16)acc[mt][nt][r];
          *reinterpret_cast<bf16x4*>(vtb + (size_t)hh * HD * S_LEN + (size_t)d * S_LEN + sb) = pk;
        }
    } else {  // Q or K: RoPE (+ 1/sqrt(D) folded into Q)
      float invf[4];
#pragma unroll
      for (int j = 0; j < 4; ++j)
        invf[j] = exp2f(-(float)(j * 16 + li) * (13.287712379549449f / 64.0f)); // 10000^(-i/64)
      bf16* dst = (seg == 0) ? (qb + (size_t)hh * S_LEN * HD)
                             : (kb + (size_t)hh * S_LEN * HD);
      const float qscale = (seg == 0) ? 0.08838834764831845f : 1.0f;
#pragma unroll
      for (int mt = 0; mt < 2; ++mt)
#pragma unroll
        for (int r = 0; r < 4; ++r) {
          const int spos = row_base + mt * 16 + lh * 4 + r;
          float cs[4], sn[4];
#pragma unroll
          for (int j = 0; j < 4; ++j) sincosf((float)spos * invf[j], &sn[j], &cs[j]);
#pragma unroll
          for (int nt = 0; nt < 8; ++nt) {
            const int d = nt * 16 + li;
            const int j = nt & 3;
            const float x = acc[mt][nt][r];
            const float prt = acc[mt][nt ^ 4][r];
            const float rot = (nt < 4) ? -prt : prt;
            const float y = (x * cs[j] + rot * sn[j]) * qscale;
            dst[(size_t)spos * HD + d] = (bf16)y;
          }
        }
    }
  }
}

// ---------------- flash attention, KV-split: 4 waves per (16 q-rows, head) ----------------
// Wave w handles KV tiles t (32 rows each) with t % 4 == w, then the partials
// (m, l, o) are merged through LDS. Q pre-scaled by 1/sqrt(D). V is [kh][d][s].
__global__ __launch_bounds__(256, 4) void attn_kernel(
    const bf16* __restrict__ qb, const bf16* __restrict__ kb, const bf16* __restrict__ vtb,
    bf16* __restrict__ ctx)
{
  __shared__ __align__(16) bf16 Pl[4 * 16 * 32];   // per-wave private P staging
  __shared__ float Ml[4][16], Ll[4][16], Lgl[16];
  __shared__ __align__(16) float Ob[16][132];      // +4 pad: spread lh groups across banks

  const int tid = threadIdx.x;
  const int w  = tid >> 6;
  const int l  = tid & 63;
  const int li = l & 15, lh = l >> 4;
  const int qt = (int)gridDim.x - 1 - (int)blockIdx.x;  // longest blocks dispatch first
  const int q0 = qt * 16;
  const int h  = blockIdx.y;
  const int kh = h >> 2;   // rep = H/KVH = 4

  const bf16* Qh = qb + (size_t)h * S_LEN * HD;
  const bf16* Kh = kb + (size_t)kh * S_LEN * HD;
  const bf16* Vh = vtb + (size_t)kh * HD * S_LEN;
  bf16* Pw = Pl + w * (16 * 32);

  bf16x8 aq[4];
#pragma unroll
  for (int kc = 0; kc < 4; ++kc)
    aq[kc] = *reinterpret_cast<const bf16x8*>(Qh + (size_t)(q0 + li) * HD + kc * 32 + lh * 8);

  f32x4 o[8];
#pragma unroll
  for (int i = 0; i < 8; ++i) o[i] = f32x4{0.f, 0.f, 0.f, 0.f};
  float mrow[4] = {-__builtin_inff(), -__builtin_inff(), -__builtin_inff(), -__builtin_inff()};
  float lrow[4] = {0.f, 0.f, 0.f, 0.f};
  const float L2E = 1.4426950408889634f;

  for (int kv0 = w * 32; kv0 < q0 + 16; kv0 += 128) {
    f32x4 sacc[2];
    sacc[0] = f32x4{0.f, 0.f, 0.f, 0.f};
    sacc[1] = f32x4{0.f, 0.f, 0.f, 0.f};
#pragma unroll
    for (int n = 0; n < 2; ++n)
#pragma unroll
      for (int kc = 0; kc < 4; ++kc) {
        bf16x8 bk = *reinterpret_cast<const bf16x8*>(
            Kh + (size_t)(kv0 + n * 16 + li) * HD + kc * 32 + lh * 8);
        sacc[n] = mfma16(aq[kc], bk, sacc[n]);
      }
    if (kv0 + 31 > q0) {  // causal mask needed on this tile
#pragma unroll
      for (int n = 0; n < 2; ++n)
#pragma unroll
        for (int r = 0; r < 4; ++r) {
          const int kv = kv0 + n * 16 + li;
          const int qq = q0 + lh * 4 + r;
          if (kv > qq) sacc[n][r] = -__builtin_inff();
        }
    }
    // online softmax (rows live on 16-lane groups; regs are rows)
    float sc[4], pm[4];
#pragma unroll
    for (int r = 0; r < 4; ++r) {
      float v = fmaxf(sacc[0][r], sacc[1][r]);
#pragma unroll
      for (int m = 1; m <= 8; m <<= 1) v = fmaxf(v, __shfl_xor(v, m));
      const float mn = fmaxf(mrow[r], v);
      sc[r] = exp2f((mrow[r] - mn) * L2E);
      mrow[r] = mn; pm[r] = mn;
    }
    float p[2][4];
#pragma unroll
    for (int r = 0; r < 4; ++r) {
      p[0][r] = exp2f((sacc[0][r] - pm[r]) * L2E);
      p[1][r] = exp2f((sacc[1][r] - pm[r]) * L2E);
      float s2 = p[0][r] + p[1][r];
#pragma unroll
      for (int m = 1; m <= 8; m <<= 1) s2 += __shfl_xor(s2, m);
      lrow[r] = lrow[r] * sc[r] + s2;
    }
#pragma unroll
    for (int dt = 0; dt < 8; ++dt)
#pragma unroll
      for (int r = 0; r < 4; ++r) o[dt][r] *= sc[r];
    // P -> wave-private LDS (C-layout positions), read back as A-fragment.
    // No barrier: intra-wave ds_write -> ds_read ordering via lgkmcnt.
#pragma unroll
    for (int n = 0; n < 2; ++n)
#pragma unroll
      for (int r = 0; r < 4; ++r)
        Pw[(lh * 4 + r) * 32 + n * 16 + li] = (bf16)p[n][r];
    const bf16x8 pa = *reinterpret_cast<const bf16x8*>(Pw + li * 32 + lh * 8);
#pragma unroll
    for (int dt = 0; dt < 8; ++dt) {
      bf16x8 bv = *reinterpret_cast<const bf16x8*>(
          Vh + (size_t)(dt * 16 + li) * S_LEN + kv0 + lh * 8);
      o[dt] = mfma16(pa, bv, o[dt]);
    }
  }

  // ---- merge the 4 KV-split partials ----
  if (li == 0) {
#pragma unroll
    for (int r = 0; r < 4; ++r) {
      Ml[w][lh * 4 + r] = mrow[r];
      Ll[w][lh * 4 + r] = lrow[r];
    }
  }
  __syncthreads();
  float sc2[4];
  {
    float lg[4];
#pragma unroll
    for (int r = 0; r < 4; ++r) {
      const int row = lh * 4 + r;
      const float m0v = Ml[0][row], m1v = Ml[1][row], m2v = Ml[2][row], m3v = Ml[3][row];
      const float mg = fmaxf(fmaxf(m0v, m1v), fmaxf(m2v, m3v));
      lg[r] = Ll[0][row] * exp2f((m0v - mg) * L2E)
            + Ll[1][row] * exp2f((m1v - mg) * L2E)
            + Ll[2][row] * exp2f((m2v - mg) * L2E)
            + Ll[3][row] * exp2f((m3v - mg) * L2E);
      sc2[r] = exp2f((mrow[r] - mg) * L2E);
    }
    if (w == 0 && li == 0) {
#pragma unroll
      for (int r = 0; r < 4; ++r) Lgl[lh * 4 + r] = lg[r];
    }
  }
#pragma unroll
  for (int pass = 0; pass < 4; ++pass) {
    if (w == pass) {
#pragma unroll
      for (int dt = 0; dt < 8; ++dt)
#pragma unroll
        for (int r = 0; r < 4; ++r) {
          const int row = lh * 4 + r, col = dt * 16 + li;
          const float v = o[dt][r] * sc2[r];
          if (pass == 0) Ob[row][col] = v; else Ob[row][col] += v;
        }
    }
    __syncthreads();
  }
  // final write: 256 threads, each 8 contiguous d
  {
    const int row = tid >> 4;
    const int d0 = (tid & 15) * 8;
    const float linv = 1.0f / Lgl[row];
    bf16x8 pk;
#pragma unroll
    for (int j = 0; j < 8; ++j) pk[j] = (bf16)(Ob[row][d0 + j] * linv);
    *reinterpret_cast<bf16x8*>(ctx + (size_t)(q0 + row) * (NH * HD) + h * HD + d0) = pk;
  }
}

extern "C" void kernel_launch(void* const* d_in, const int* in_sizes, int n_in,
                              void* d_out, int out_size, void* d_ws, size_t ws_size,
                              hipStream_t stream)
{
  const float* x       = (const float*)d_in[0];
  const float* w_qkv   = (const float*)d_in[1];
  const float* w_dense = (const float*)d_in[2];
  float* out = (float*)d_out;

  char* ws = (char*)d_ws;
  size_t off = 0;
  bf16* xb    = (bf16*)(ws + off); off += (size_t)S_LEN * EMB * 2;
  bf16* wqkvb = (bf16*)(ws + off); off += (size_t)FQKV * EMB * 2;
  bf16* wdb   = (bf16*)(ws + off); off += (size_t)EMB * EMB * 2;
  bf16* qbuf  = (bf16*)(ws + off); off += (size_t)NH  * S_LEN * HD * 2;
  bf16* kbuf  = (bf16*)(ws + off); off += (size_t)NKV * S_LEN * HD * 2;
  bf16* vtbuf = (bf16*)(ws + off); off += (size_t)NKV * HD * S_LEN * 2;
  bf16* ctxb  = (bf16*)(ws + off); off += (size_t)S_LEN * NH * HD * 2;
  (void)ws_size; (void)in_sizes; (void)n_in; (void)out_size;

  cvt_kernel<<<2048, 256, 0, stream>>>(x,       xb,    S_LEN * EMB / 4);
  cvt_kernel<<<2048, 256, 0, stream>>>(w_qkv,   wqkvb, FQKV * EMB / 4);
  cvt_kernel<<<2048, 256, 0, stream>>>(w_dense, wdb,   EMB * EMB / 4);

  gemm_bt<<<dim3(FQKV / 128, S_LEN / 128), 256, 0, stream>>>(
      xb, wqkvb, S_LEN, FQKV, EMB, 0, qbuf, kbuf, vtbuf, nullptr);

  attn_kernel<<<dim3(S_LEN / 16, NH), 256, 0, stream>>>(qbuf, kbuf, vtbuf, ctxb);

  gemm_bt<<<dim3(EMB / 128, S_LEN / 128), 256, 0, stream>>>(
      ctxb, wdb, S_LEN, EMB, NH * HD, 1, nullptr, nullptr, nullptr, out);
}

// Round 3
// 276.736 us; speedup vs baseline: 1.1843x; 1.0292x over previous
//
#include <hip/hip_runtime.h>
#include <hip/hip_bf16.h>
#include <math.h>

typedef __bf16 bf16;
typedef __bf16 bf16x4 __attribute__((ext_vector_type(4)));
typedef __bf16 bf16x8 __attribute__((ext_vector_type(8)));
typedef float  f32x4  __attribute__((ext_vector_type(4)));
typedef float  f32x16 __attribute__((ext_vector_type(16)));

#define S_LEN 2048
#define EMB   2048
#define NH    16
#define NKV   4
#define HD    128
#define FQKV  3072  /* NH*HD + 2*NKV*HD */

__device__ __forceinline__ f32x4 mfma16(bf16x8 a, bf16x8 b, f32x4 c) {
  return __builtin_amdgcn_mfma_f32_16x16x32_bf16(a, b, c, 0, 0, 0);
}
__device__ __forceinline__ f32x16 mfma32(bf16x8 a, bf16x8 b, f32x16 c) {
  return __builtin_amdgcn_mfma_f32_32x32x16_bf16(a, b, c, 0, 0, 0);
}
__device__ __forceinline__ f32x16 zero16() {
  f32x16 v;
#pragma unroll
  for (int i = 0; i < 16; ++i) v[i] = 0.f;
  return v;
}

// ---------------- f32 -> bf16 convert, 4-wide ----------------
__global__ void cvt_kernel(const float* __restrict__ in, bf16* __restrict__ out, int n4) {
  int i = blockIdx.x * blockDim.x + threadIdx.x;
  const int stride = gridDim.x * blockDim.x;
  for (; i < n4; i += stride) {
    float4 v = reinterpret_cast<const float4*>(in)[i];
    bf16x4 o;
    o[0] = (bf16)v.x; o[1] = (bf16)v.y; o[2] = (bf16)v.z; o[3] = (bf16)v.w;
    reinterpret_cast<bf16x4*>(out)[i] = o;
  }
}

// ---------------- GEMM: C[M][N] = A[M][K] * B[N][K]^T (both row-major in K) ----------------
__global__ __launch_bounds__(256, 2) void gemm_bt(
    const bf16* __restrict__ A, const bf16* __restrict__ B,
    int M, int N, int K, int mode,
    bf16* __restrict__ qb, bf16* __restrict__ kb, bf16* __restrict__ vtb,
    float* __restrict__ outf)
{
  __shared__ __align__(16) bf16 As[128 * 64];
  __shared__ __align__(16) bf16 Bs[128 * 64];
  const int tid = threadIdx.x;
  const int w  = tid >> 6;
  const int l  = tid & 63;
  const int li = l & 15, lh = l >> 4;
  const int m0 = blockIdx.y * 128, n0 = blockIdx.x * 128;

  f32x4 acc[2][8];
#pragma unroll
  for (int i = 0; i < 2; ++i)
#pragma unroll
    for (int j = 0; j < 8; ++j) acc[i][j] = f32x4{0.f, 0.f, 0.f, 0.f};

  const int srow = l >> 3;   // row within an 8-row staging group
  const int schk = l & 7;    // 16B chunk within a 64-col row

  for (int k0 = 0; k0 < K; k0 += 64) {
#pragma unroll
    for (int i = 0; i < 4; ++i) {
      const int row = i * 32 + w * 8 + srow;
      const int sch = schk ^ (row & 7);
      const bf16* ga = A + (size_t)(m0 + row) * K + (k0 + sch * 8);
      const bf16* gb = B + (size_t)(n0 + row) * K + (k0 + sch * 8);
      bf16* la = As + (i * 32 + w * 8) * 64;
      bf16* lb = Bs + (i * 32 + w * 8) * 64;
      __builtin_amdgcn_global_load_lds((const __attribute__((address_space(1))) void*)ga,
                                       (__attribute__((address_space(3))) void*)la, 16, 0, 0);
      __builtin_amdgcn_global_load_lds((const __attribute__((address_space(1))) void*)gb,
                                       (__attribute__((address_space(3))) void*)lb, 16, 0, 0);
    }
    __syncthreads();
#pragma unroll
    for (int kc = 0; kc < 2; ++kc) {
      bf16x8 afr[2], bfr[8];
#pragma unroll
      for (int mt = 0; mt < 2; ++mt) {
        const int mr = w * 32 + mt * 16 + li;
        const int c  = (kc * 4 + lh) ^ (mr & 7);
        afr[mt] = *reinterpret_cast<const bf16x8*>((const char*)As + mr * 128 + c * 16);
      }
#pragma unroll
      for (int nt = 0; nt < 8; ++nt) {
        const int nr = nt * 16 + li;
        const int c  = (kc * 4 + lh) ^ (nr & 7);
        bfr[nt] = *reinterpret_cast<const bf16x8*>((const char*)Bs + nr * 128 + c * 16);
      }
#pragma unroll
      for (int nt = 0; nt < 8; ++nt) {
        acc[0][nt] = mfma16(afr[0], bfr[nt], acc[0][nt]);
        acc[1][nt] = mfma16(afr[1], bfr[nt], acc[1][nt]);
      }
    }
    __syncthreads();
  }

  // ---- epilogue ----
  const int row_base = m0 + w * 32;
  if (mode == 1) {
#pragma unroll
    for (int mt = 0; mt < 2; ++mt)
#pragma unroll
      for (int nt = 0; nt < 8; ++nt)
#pragma unroll
        for (int r = 0; r < 4; ++r) {
          const int sr = row_base + mt * 16 + lh * 4 + r;
          const int sc = n0 + nt * 16 + li;
          outf[(size_t)sr * N + sc] = acc[mt][nt][r];
        }
  } else {
    int seg, hh;
    if (n0 < NH * HD)            { seg = 0; hh = n0 >> 7; }
    else if (n0 < (NH + NKV) * HD){ seg = 1; hh = (n0 - NH * HD) >> 7; }
    else                          { seg = 2; hh = (n0 - (NH + NKV) * HD) >> 7; }

    if (seg == 2) {  // V: store transposed vtb[kh][d][s], pack 4 consecutive s
#pragma unroll
      for (int mt = 0; mt < 2; ++mt)
#pragma unroll
        for (int nt = 0; nt < 8; ++nt) {
          const int d = nt * 16 + li;
          const int sb = row_base + mt * 16 + lh * 4;
          bf16x4 pk;
#pragma unroll
          for (int r = 0; r < 4; ++r) pk[r] = (bf16)acc[mt][nt][r];
          *reinterpret_cast<bf16x4*>(vtb + (size_t)hh * HD * S_LEN + (size_t)d * S_LEN + sb) = pk;
        }
    } else {  // Q or K: RoPE (+ 1/sqrt(D) folded into Q)
      float invf[4];
#pragma unroll
      for (int j = 0; j < 4; ++j)
        invf[j] = exp2f(-(float)(j * 16 + li) * (13.287712379549449f / 64.0f)); // 10000^(-i/64)
      bf16* dst = (seg == 0) ? (qb + (size_t)hh * S_LEN * HD)
                             : (kb + (size_t)hh * S_LEN * HD);
      const float qscale = (seg == 0) ? 0.08838834764831845f : 1.0f;
#pragma unroll
      for (int mt = 0; mt < 2; ++mt)
#pragma unroll
        for (int r = 0; r < 4; ++r) {
          const int spos = row_base + mt * 16 + lh * 4 + r;
          float cs[4], sn[4];
#pragma unroll
          for (int j = 0; j < 4; ++j) sincosf((float)spos * invf[j], &sn[j], &cs[j]);
#pragma unroll
          for (int nt = 0; nt < 8; ++nt) {
            const int d = nt * 16 + li;
            const int j = nt & 3;
            const float x = acc[mt][nt][r];
            const float prt = acc[mt][nt ^ 4][r];
            const float rot = (nt < 4) ? -prt : prt;
            const float y = (x * cs[j] + rot * sn[j]) * qscale;
            dst[(size_t)spos * HD + d] = (bf16)y;
          }
        }
    }
  }
}

// ---------------- flash attention, swapped-QK^T 32x32 + KV-split ----------------
// Block = 4 waves on the SAME 32 q-rows; wave w takes KV tiles kv0 = w*32 + 128t.
// S^T = mfma32(K, Q): lane holds q = l&31, 16 kv values (half per lane pair).
// Softmax fully in-register (15 fmax + 1 shfl_xor(32)); P regs feed PV MFMA
// directly as B-fragment (slot order == C-row order, both lane halves consistent).
// V^T[kh][d][s] rows are the A-fragment. Partials merged via LDS at the end.
__global__ __launch_bounds__(256, 2) void attn_kernel(
    const bf16* __restrict__ qb, const bf16* __restrict__ kb, const bf16* __restrict__ vtb,
    bf16* __restrict__ ctx)
{
  __shared__ float Ml[4][32], Ll[4][32], Lgl[32];
  __shared__ float Obuf[4][32][129];   // stride 129: conflict-free column writes

  const int tid = threadIdx.x;
  const int w  = tid >> 6;
  const int l  = tid & 63;
  const int lq = l & 31;     // q index within tile (C col / B row)
  const int hi = l >> 5;     // lane half (C row group / k-slot group)
  const int qt = (int)gridDim.x - 1 - (int)blockIdx.x;  // longest first
  const int q0 = qt * 32;
  const int h  = blockIdx.y;
  const int kh = h >> 2;     // rep = 4

  const bf16* Qh = qb + (size_t)h * S_LEN * HD;
  const bf16* Kh = kb + (size_t)kh * S_LEN * HD;
  const bf16* Vh = vtb + (size_t)kh * HD * S_LEN;

  const float L2E = 1.4426950408889634f;
  const float BIG = -3.0e38f;   // finite mask value: no NaN paths

  // hoist Q fragments: lane -> q-row (q0+lq), d = kc*16 + hi*8 + {0..7}
  bf16x8 qfr[8];
#pragma unroll
  for (int kc = 0; kc < 8; ++kc)
    qfr[kc] = *reinterpret_cast<const bf16x8*>(Qh + (size_t)(q0 + lq) * HD + kc * 16 + hi * 8);

  f32x16 o[4];
#pragma unroll
  for (int dt = 0; dt < 4; ++dt) o[dt] = zero16();
  float mrow = BIG, lrow = 0.f;

  for (int kv0 = w * 32; kv0 < q0 + 32; kv0 += 128) {
    // ---- QK^T: S^T[kv][q] ----
    f32x16 s = zero16();
#pragma unroll
    for (int kc = 0; kc < 8; ++kc) {
      bf16x8 kf = *reinterpret_cast<const bf16x8*>(
          Kh + (size_t)(kv0 + lq) * HD + kc * 16 + hi * 8);
      s = mfma32(kf, qfr[kc], s);
    }
    // ---- causal mask (diagonal tiles only) ----
    const int q = q0 + lq;
    if (kv0 + 31 > q0) {
#pragma unroll
      for (int r = 0; r < 16; ++r) {
        const int kvv = (r & 3) + 8 * (r >> 2) + 4 * hi;
        if (kv0 + kvv > q) s[r] = BIG;
      }
    }
    // ---- in-register online softmax with defer-max (THR=8) ----
    float pm = s[0];
#pragma unroll
    for (int r = 1; r < 16; ++r) pm = fmaxf(pm, s[r]);
    pm = fmaxf(pm, __shfl_xor(pm, 32));
    if (__any(pm > mrow + 8.f)) {
      const float mnew = fmaxf(mrow, pm);
      const float sc = (mrow < -1.0e37f) ? 0.f : exp2f((mrow - mnew) * L2E);
      mrow = mnew;
      lrow *= sc;
#pragma unroll
      for (int dt = 0; dt < 4; ++dt) o[dt] = o[dt] * sc;
    }
    bf16x8 pb0, pb1;
    float tsum = 0.f;
#pragma unroll
    for (int r = 0; r < 8; ++r) {
      const float pv = exp2f((s[r] - mrow) * L2E);
      tsum += pv; pb0[r] = (bf16)pv;
    }
#pragma unroll
    for (int r = 0; r < 8; ++r) {
      const float pv = exp2f((s[8 + r] - mrow) * L2E);
      tsum += pv; pb1[r] = (bf16)pv;
    }
    tsum += __shfl_xor(tsum, 32);
    lrow += tsum;
    // ---- PV: O^T[d][q] += V^T[d][kv] * P ----
    // k-slot map (matches P reg order): MFMA#1 kv = {0-3,8-11}(hi=0)/{4-7,12-15}(hi=1)
#pragma unroll
    for (int dt = 0; dt < 4; ++dt) {
      const bf16* vrow = Vh + (size_t)(dt * 32 + lq) * S_LEN + kv0 + 4 * hi;
      bf16x4 a0 = *reinterpret_cast<const bf16x4*>(vrow);
      bf16x4 a1 = *reinterpret_cast<const bf16x4*>(vrow + 8);
      bf16x4 a2 = *reinterpret_cast<const bf16x4*>(vrow + 16);
      bf16x4 a3 = *reinterpret_cast<const bf16x4*>(vrow + 24);
      bf16x8 A1, A2;
#pragma unroll
      for (int j = 0; j < 4; ++j) {
        A1[j] = a0[j]; A1[4 + j] = a1[j];
        A2[j] = a2[j]; A2[4 + j] = a3[j];
      }
      o[dt] = mfma32(A1, pb0, o[dt]);
      o[dt] = mfma32(A2, pb1, o[dt]);
    }
  }

  // ---- merge the 4 KV-split partials ----
  if (hi == 0) { Ml[w][lq] = mrow; Ll[w][lq] = lrow; }
  __syncthreads();
  const float m0v = Ml[0][lq], m1v = Ml[1][lq], m2v = Ml[2][lq], m3v = Ml[3][lq];
  const float mg = fmaxf(fmaxf(m0v, m1v), fmaxf(m2v, m3v));
  const float lg = Ll[0][lq] * exp2f((m0v - mg) * L2E)
                 + Ll[1][lq] * exp2f((m1v - mg) * L2E)
                 + Ll[2][lq] * exp2f((m2v - mg) * L2E)
                 + Ll[3][lq] * exp2f((m3v - mg) * L2E);
  const float sc2 = (mrow < -1.0e37f) ? 0.f : exp2f((mrow - mg) * L2E);
  if (w == 0 && hi == 0) Lgl[lq] = lg;
#pragma unroll
  for (int dt = 0; dt < 4; ++dt)
#pragma unroll
    for (int r = 0; r < 16; ++r) {
      const int d = dt * 32 + (r & 3) + 8 * (r >> 2) + 4 * hi;
      Obuf[w][lq][d] = o[dt][r] * sc2;
    }
  __syncthreads();
  // ---- epilogue: 256 threads, row = tid>>3, 16 d each ----
  {
    const int row = tid >> 3;
    const int d0 = (tid & 7) * 16;
    const float linv = 1.0f / Lgl[row];
    bf16x8 pk0, pk1;
#pragma unroll
    for (int j = 0; j < 8; ++j) {
      const float v0 = (Obuf[0][row][d0 + j] + Obuf[1][row][d0 + j]
                      + Obuf[2][row][d0 + j] + Obuf[3][row][d0 + j]) * linv;
      const float v1 = (Obuf[0][row][d0 + 8 + j] + Obuf[1][row][d0 + 8 + j]
                      + Obuf[2][row][d0 + 8 + j] + Obuf[3][row][d0 + 8 + j]) * linv;
      pk0[j] = (bf16)v0; pk1[j] = (bf16)v1;
    }
    bf16* dst = ctx + (size_t)(q0 + row) * (NH * HD) + h * HD + d0;
    *reinterpret_cast<bf16x8*>(dst) = pk0;
    *reinterpret_cast<bf16x8*>(dst + 8) = pk1;
  }
}

extern "C" void kernel_launch(void* const* d_in, const int* in_sizes, int n_in,
                              void* d_out, int out_size, void* d_ws, size_t ws_size,
                              hipStream_t stream)
{
  const float* x       = (const float*)d_in[0];
  const float* w_qkv   = (const float*)d_in[1];
  const float* w_dense = (const float*)d_in[2];
  float* out = (float*)d_out;

  char* ws = (char*)d_ws;
  size_t off = 0;
  bf16* xb    = (bf16*)(ws + off); off += (size_t)S_LEN * EMB * 2;
  bf16* wqkvb = (bf16*)(ws + off); off += (size_t)FQKV * EMB * 2;
  bf16* wdb   = (bf16*)(ws + off); off += (size_t)EMB * EMB * 2;
  bf16* qbuf  = (bf16*)(ws + off); off += (size_t)NH  * S_LEN * HD * 2;
  bf16* kbuf  = (bf16*)(ws + off); off += (size_t)NKV * S_LEN * HD * 2;
  bf16* vtbuf = (bf16*)(ws + off); off += (size_t)NKV * HD * S_LEN * 2;
  bf16* ctxb  = (bf16*)(ws + off); off += (size_t)S_LEN * NH * HD * 2;
  (void)ws_size; (void)in_sizes; (void)n_in; (void)out_size;

  cvt_kernel<<<2048, 256, 0, stream>>>(x,       xb,    S_LEN * EMB / 4);
  cvt_kernel<<<2048, 256, 0, stream>>>(w_qkv,   wqkvb, FQKV * EMB / 4);
  cvt_kernel<<<2048, 256, 0, stream>>>(w_dense, wdb,   EMB * EMB / 4);

  gemm_bt<<<dim3(FQKV / 128, S_LEN / 128), 256, 0, stream>>>(
      xb, wqkvb, S_LEN, FQKV, EMB, 0, qbuf, kbuf, vtbuf, nullptr);

  attn_kernel<<<dim3(S_LEN / 32, NH), 256, 0, stream>>>(qbuf, kbuf, vtbuf, ctxb);

  gemm_bt<<<dim3(EMB / 128, S_LEN / 128), 256, 0, stream>>>(
      ctxb, wdb, S_LEN, EMB, NH * HD, 1, nullptr, nullptr, nullptr, out);
}

// Round 4
// 195.813 us; speedup vs baseline: 1.6738x; 1.4133x over previous
//
#include <hip/hip_runtime.h>
#include <hip/hip_bf16.h>
#include <math.h>

typedef __bf16 bf16;
typedef __bf16 bf16x4 __attribute__((ext_vector_type(4)));
typedef __bf16 bf16x8 __attribute__((ext_vector_type(8)));
typedef float  f32x4  __attribute__((ext_vector_type(4)));
typedef float  f32x16 __attribute__((ext_vector_type(16)));

#define S_LEN 2048
#define EMB   2048
#define NH    16
#define NKV   4
#define HD    128
#define FQKV  3072  /* NH*HD + 2*NKV*HD */

__device__ __forceinline__ f32x4 mfma16(bf16x8 a, bf16x8 b, f32x4 c) {
  return __builtin_amdgcn_mfma_f32_16x16x32_bf16(a, b, c, 0, 0, 0);
}
__device__ __forceinline__ f32x16 mfma32(bf16x8 a, bf16x8 b, f32x16 c) {
  return __builtin_amdgcn_mfma_f32_32x32x16_bf16(a, b, c, 0, 0, 0);
}
__device__ __forceinline__ f32x16 zero16() {
  f32x16 v;
#pragma unroll
  for (int i = 0; i < 16; ++i) v[i] = 0.f;
  return v;
}

// ---------------- f32 -> bf16 convert, 4-wide ----------------
__global__ void cvt_kernel(const float* __restrict__ in, bf16* __restrict__ out, int n4) {
  int i = blockIdx.x * blockDim.x + threadIdx.x;
  const int stride = gridDim.x * blockDim.x;
  for (; i < n4; i += stride) {
    float4 v = reinterpret_cast<const float4*>(in)[i];
    bf16x4 o;
    o[0] = (bf16)v.x; o[1] = (bf16)v.y; o[2] = (bf16)v.z; o[3] = (bf16)v.w;
    reinterpret_cast<bf16x4*>(out)[i] = o;
  }
}

// ---------------- GEMM: C[M][N] = A[M][K] * B[N][K]^T (both row-major in K) ----------------
// mode 0: fused RoPE/split epilogue -> qb[h][s][d], kb[kh][s][d],
//         vtb = V in PV-fragment-ready layout: vf[kh][tile][d][32 perm kv]
// mode 1: plain f32 store to outf[row*N + col]
__global__ __launch_bounds__(256, 2) void gemm_bt(
    const bf16* __restrict__ A, const bf16* __restrict__ B,
    int M, int N, int K, int mode,
    bf16* __restrict__ qb, bf16* __restrict__ kb, bf16* __restrict__ vtb,
    float* __restrict__ outf)
{
  __shared__ __align__(16) bf16 As[128 * 64];
  __shared__ __align__(16) bf16 Bs[128 * 64];
  const int tid = threadIdx.x;
  const int w  = tid >> 6;
  const int l  = tid & 63;
  const int li = l & 15, lh = l >> 4;
  const int m0 = blockIdx.y * 128, n0 = blockIdx.x * 128;

  f32x4 acc[2][8];
#pragma unroll
  for (int i = 0; i < 2; ++i)
#pragma unroll
    for (int j = 0; j < 8; ++j) acc[i][j] = f32x4{0.f, 0.f, 0.f, 0.f};

  const int srow = l >> 3;   // row within an 8-row staging group
  const int schk = l & 7;    // 16B chunk within a 64-col row

  for (int k0 = 0; k0 < K; k0 += 64) {
#pragma unroll
    for (int i = 0; i < 4; ++i) {
      const int row = i * 32 + w * 8 + srow;
      const int sch = schk ^ (row & 7);
      const bf16* ga = A + (size_t)(m0 + row) * K + (k0 + sch * 8);
      const bf16* gb = B + (size_t)(n0 + row) * K + (k0 + sch * 8);
      bf16* la = As + (i * 32 + w * 8) * 64;
      bf16* lb = Bs + (i * 32 + w * 8) * 64;
      __builtin_amdgcn_global_load_lds((const __attribute__((address_space(1))) void*)ga,
                                       (__attribute__((address_space(3))) void*)la, 16, 0, 0);
      __builtin_amdgcn_global_load_lds((const __attribute__((address_space(1))) void*)gb,
                                       (__attribute__((address_space(3))) void*)lb, 16, 0, 0);
    }
    __syncthreads();
#pragma unroll
    for (int kc = 0; kc < 2; ++kc) {
      bf16x8 afr[2], bfr[8];
#pragma unroll
      for (int mt = 0; mt < 2; ++mt) {
        const int mr = w * 32 + mt * 16 + li;
        const int c  = (kc * 4 + lh) ^ (mr & 7);
        afr[mt] = *reinterpret_cast<const bf16x8*>((const char*)As + mr * 128 + c * 16);
      }
#pragma unroll
      for (int nt = 0; nt < 8; ++nt) {
        const int nr = nt * 16 + li;
        const int c  = (kc * 4 + lh) ^ (nr & 7);
        bfr[nt] = *reinterpret_cast<const bf16x8*>((const char*)Bs + nr * 128 + c * 16);
      }
#pragma unroll
      for (int nt = 0; nt < 8; ++nt) {
        acc[0][nt] = mfma16(afr[0], bfr[nt], acc[0][nt]);
        acc[1][nt] = mfma16(afr[1], bfr[nt], acc[1][nt]);
      }
    }
    __syncthreads();
  }

  // ---- epilogue ----
  const int row_base = m0 + w * 32;
  if (mode == 1) {
#pragma unroll
    for (int mt = 0; mt < 2; ++mt)
#pragma unroll
      for (int nt = 0; nt < 8; ++nt)
#pragma unroll
        for (int r = 0; r < 4; ++r) {
          const int sr = row_base + mt * 16 + lh * 4 + r;
          const int sc = n0 + nt * 16 + li;
          outf[(size_t)sr * N + sc] = acc[mt][nt][r];
        }
  } else {
    int seg, hh;
    if (n0 < NH * HD)            { seg = 0; hh = n0 >> 7; }
    else if (n0 < (NH + NKV) * HD){ seg = 1; hh = (n0 - NH * HD) >> 7; }
    else                          { seg = 2; hh = (n0 - (NH + NKV) * HD) >> 7; }

    if (seg == 2) {
      // V -> fragment-ready layout vf[kh][T][d][32]:
      // elems [0..7]=kv{0-3,8-11}, [8..15]={16-19,24-27}, [16..23]={4-7,12-15}, [24..31]={20-23,28-31}
      const int T = row_base >> 5;            // 32-row kv tile (same for mt=0,1)
#pragma unroll
      for (int mt = 0; mt < 2; ++mt) {
        const int qp = mt * 4 + lh;           // ss>>2, ss = mt*16+lh*4+r
        const int pq = (qp >> 1) + (qp & 1) * 4;
#pragma unroll
        for (int nt = 0; nt < 8; ++nt) {
          const int d = nt * 16 + li;
          bf16x4 pk;
#pragma unroll
          for (int r = 0; r < 4; ++r) pk[r] = (bf16)acc[mt][nt][r];
          *reinterpret_cast<bf16x4*>(
              vtb + ((size_t)(hh * 64 + T) * 128 + d) * 32 + pq * 4) = pk;
        }
      }
    } else {  // Q or K: RoPE (+ 1/sqrt(D) folded into Q)
      float invf[4];
#pragma unroll
      for (int j = 0; j < 4; ++j)
        invf[j] = exp2f(-(float)(j * 16 + li) * (13.287712379549449f / 64.0f)); // 10000^(-i/64)
      bf16* dst = (seg == 0) ? (qb + (size_t)hh * S_LEN * HD)
                             : (kb + (size_t)hh * S_LEN * HD);
      const float qscale = (seg == 0) ? 0.08838834764831845f : 1.0f;
#pragma unroll
      for (int mt = 0; mt < 2; ++mt)
#pragma unroll
        for (int r = 0; r < 4; ++r) {
          const int spos = row_base + mt * 16 + lh * 4 + r;
          float cs[4], sn[4];
#pragma unroll
          for (int j = 0; j < 4; ++j) sincosf((float)spos * invf[j], &sn[j], &cs[j]);
#pragma unroll
          for (int nt = 0; nt < 8; ++nt) {
            const int d = nt * 16 + li;
            const int j = nt & 3;
            const float x = acc[mt][nt][r];
            const float prt = acc[mt][nt ^ 4][r];
            const float rot = (nt < 4) ? -prt : prt;
            const float y = (x * cs[j] + rot * sn[j]) * qscale;
            dst[(size_t)spos * HD + d] = (bf16)y;
          }
        }
    }
  }
}

// ---------------- flash attention, swapped-QK^T 32x32 + KV-split ----------------
// Block = 4 waves on the SAME 32 q-rows; wave w takes KV tiles kv0 = w*32 + 128t.
// S^T = mfma32(K, Q); softmax fully in-register; P feeds PV as B-fragment; V is
// pre-permuted so the PV A-fragment is two contiguous b128 loads per d-tile.
// Partials merged once per block through a single shared f32 Obuf (4 passes).
__global__ __launch_bounds__(256, 3) void attn_kernel(
    const bf16* __restrict__ qb, const bf16* __restrict__ kb, const bf16* __restrict__ vtb,
    bf16* __restrict__ ctx)
{
  __shared__ float Ml[4][32], Ll[4][32], Lgl[32];
  __shared__ float Obuf[32][129];   // stride 129: conflict-free column writes

  const int tid = threadIdx.x;
  const int w  = tid >> 6;
  const int l  = tid & 63;
  const int lq = l & 31;     // q index within tile (C col / B row)
  const int hi = l >> 5;     // lane half (C row group / k-slot group)
  const int qt = (int)gridDim.x - 1 - (int)blockIdx.x;  // longest first
  const int q0 = qt * 32;
  const int h  = blockIdx.y;
  const int kh = h >> 2;     // rep = 4

  const bf16* Qh = qb + (size_t)h * S_LEN * HD;
  const bf16* Kh = kb + (size_t)kh * S_LEN * HD;
  const bf16* Vf = vtb + (size_t)kh * S_LEN * HD;   // fragment-ready layout

  const float L2E = 1.4426950408889634f;
  const float BIG = -3.0e38f;   // finite mask value: no NaN paths

  // hoist Q fragments: lane -> q-row (q0+lq), d = kc*16 + hi*8 + {0..7}
  bf16x8 qfr[8];
#pragma unroll
  for (int kc = 0; kc < 8; ++kc)
    qfr[kc] = *reinterpret_cast<const bf16x8*>(Qh + (size_t)(q0 + lq) * HD + kc * 16 + hi * 8);

  f32x16 o[4];
#pragma unroll
  for (int dt = 0; dt < 4; ++dt) o[dt] = zero16();
  float mrow = BIG, lrow = 0.f;

  for (int kv0 = w * 32; kv0 < q0 + 32; kv0 += 128) {
    // ---- QK^T: S^T[kv][q], two chains of 4 ----
    f32x16 sa = zero16(), sb = zero16();
#pragma unroll
    for (int kc = 0; kc < 4; ++kc) {
      bf16x8 kfa = *reinterpret_cast<const bf16x8*>(
          Kh + (size_t)(kv0 + lq) * HD + kc * 16 + hi * 8);
      bf16x8 kfb = *reinterpret_cast<const bf16x8*>(
          Kh + (size_t)(kv0 + lq) * HD + (kc + 4) * 16 + hi * 8);
      sa = mfma32(kfa, qfr[kc], sa);
      sb = mfma32(kfb, qfr[kc + 4], sb);
    }
    f32x16 s = sa + sb;
    // ---- causal mask (diagonal tiles only) ----
    const int q = q0 + lq;
    if (kv0 + 31 > q0) {
#pragma unroll
      for (int r = 0; r < 16; ++r) {
        const int kvv = (r & 3) + 8 * (r >> 2) + 4 * hi;
        if (kv0 + kvv > q) s[r] = BIG;
      }
    }
    // ---- in-register online softmax with defer-max (THR=8) ----
    float pm = s[0];
#pragma unroll
    for (int r = 1; r < 16; ++r) pm = fmaxf(pm, s[r]);
    pm = fmaxf(pm, __shfl_xor(pm, 32));
    if (__any(pm > mrow + 8.f)) {
      const float mnew = fmaxf(mrow, pm);
      const float sc = (mrow < -1.0e37f) ? 0.f : exp2f((mrow - mnew) * L2E);
      mrow = mnew;
      lrow *= sc;
#pragma unroll
      for (int dt = 0; dt < 4; ++dt) o[dt] = o[dt] * sc;
    }
    bf16x8 pb0, pb1;
    float tsum = 0.f;
#pragma unroll
    for (int r = 0; r < 8; ++r) {
      const float pv = exp2f((s[r] - mrow) * L2E);
      tsum += pv; pb0[r] = (bf16)pv;
    }
#pragma unroll
    for (int r = 0; r < 8; ++r) {
      const float pv = exp2f((s[8 + r] - mrow) * L2E);
      tsum += pv; pb1[r] = (bf16)pv;
    }
    tsum += __shfl_xor(tsum, 32);
    lrow += tsum;
    // ---- PV: O^T[d][q] += V^T[d][kv] * P, fragment-ready V ----
    const bf16* vbase = Vf + ((size_t)(kv0 >> 5) * 128 + lq) * 32 + hi * 16;
#pragma unroll
    for (int dt = 0; dt < 4; ++dt) {
      const bf16* vrow = vbase + (size_t)(dt * 32) * 32;
      bf16x8 A1 = *reinterpret_cast<const bf16x8*>(vrow);
      bf16x8 A2 = *reinterpret_cast<const bf16x8*>(vrow + 8);
      o[dt] = mfma32(A1, pb0, o[dt]);
      o[dt] = mfma32(A2, pb1, o[dt]);
    }
  }

  // ---- merge the 4 KV-split partials (shared Obuf, serialized passes) ----
  if (hi == 0) { Ml[w][lq] = mrow; Ll[w][lq] = lrow; }
  __syncthreads();
  const float m0v = Ml[0][lq], m1v = Ml[1][lq], m2v = Ml[2][lq], m3v = Ml[3][lq];
  const float mg = fmaxf(fmaxf(m0v, m1v), fmaxf(m2v, m3v));
  const float lg = Ll[0][lq] * exp2f((m0v - mg) * L2E)
                 + Ll[1][lq] * exp2f((m1v - mg) * L2E)
                 + Ll[2][lq] * exp2f((m2v - mg) * L2E)
                 + Ll[3][lq] * exp2f((m3v - mg) * L2E);
  const float sc2 = (mrow < -1.0e37f) ? 0.f : exp2f((mrow - mg) * L2E);
  if (w == 0 && hi == 0) Lgl[lq] = lg;
#pragma unroll
  for (int pass = 0; pass < 4; ++pass) {
    if (w == pass) {
#pragma unroll
      for (int dt = 0; dt < 4; ++dt)
#pragma unroll
        for (int r = 0; r < 16; ++r) {
          const int d = dt * 32 + (r & 3) + 8 * (r >> 2) + 4 * hi;
          const float v = o[dt][r] * sc2;
          if (pass == 0) Obuf[lq][d] = v; else Obuf[lq][d] += v;
        }
    }
    __syncthreads();
  }
  // ---- epilogue: 256 threads, row = tid>>3, 16 d each ----
  {
    const int row = tid >> 3;
    const int d0 = (tid & 7) * 16;
    const float linv = 1.0f / Lgl[row];
    bf16x8 pk0, pk1;
#pragma unroll
    for (int j = 0; j < 8; ++j) {
      pk0[j] = (bf16)(Obuf[row][d0 + j] * linv);
      pk1[j] = (bf16)(Obuf[row][d0 + 8 + j] * linv);
    }
    bf16* dst = ctx + (size_t)(q0 + row) * (NH * HD) + h * HD + d0;
    *reinterpret_cast<bf16x8*>(dst) = pk0;
    *reinterpret_cast<bf16x8*>(dst + 8) = pk1;
  }
}

extern "C" void kernel_launch(void* const* d_in, const int* in_sizes, int n_in,
                              void* d_out, int out_size, void* d_ws, size_t ws_size,
                              hipStream_t stream)
{
  const float* x       = (const float*)d_in[0];
  const float* w_qkv   = (const float*)d_in[1];
  const float* w_dense = (const float*)d_in[2];
  float* out = (float*)d_out;

  char* ws = (char*)d_ws;
  size_t off = 0;
  bf16* xb    = (bf16*)(ws + off); off += (size_t)S_LEN * EMB * 2;
  bf16* wqkvb = (bf16*)(ws + off); off += (size_t)FQKV * EMB * 2;
  bf16* wdb   = (bf16*)(ws + off); off += (size_t)EMB * EMB * 2;
  bf16* qbuf  = (bf16*)(ws + off); off += (size_t)NH  * S_LEN * HD * 2;
  bf16* kbuf  = (bf16*)(ws + off); off += (size_t)NKV * S_LEN * HD * 2;
  bf16* vfbuf = (bf16*)(ws + off); off += (size_t)NKV * HD * S_LEN * 2;
  bf16* ctxb  = (bf16*)(ws + off); off += (size_t)S_LEN * NH * HD * 2;
  (void)ws_size; (void)in_sizes; (void)n_in; (void)out_size;

  cvt_kernel<<<2048, 256, 0, stream>>>(x,       xb,    S_LEN * EMB / 4);
  cvt_kernel<<<2048, 256, 0, stream>>>(w_qkv,   wqkvb, FQKV * EMB / 4);
  cvt_kernel<<<2048, 256, 0, stream>>>(w_dense, wdb,   EMB * EMB / 4);

  gemm_bt<<<dim3(FQKV / 128, S_LEN / 128), 256, 0, stream>>>(
      xb, wqkvb, S_LEN, FQKV, EMB, 0, qbuf, kbuf, vfbuf, nullptr);

  attn_kernel<<<dim3(S_LEN / 32, NH), 256, 0, stream>>>(qbuf, kbuf, vfbuf, ctxb);

  gemm_bt<<<dim3(EMB / 128, S_LEN / 128), 256, 0, stream>>>(
      ctxb, wdb, S_LEN, EMB, NH * HD, 1, nullptr, nullptr, nullptr, out);
}